// Round 4
// baseline (1570.454 us; speedup 1.0000x reference)
//
#include <hip/hip_runtime.h>
#include <hip/hip_bf16.h>
#include <stdint.h>

// ---------- bf16 helpers (raw ushort representation) ----------
__device__ inline float bf2f(ushort u) {
    union { uint32_t u; float f; } v; v.u = ((uint32_t)u) << 16; return v.f;
}
__device__ inline ushort f2bf(float f) {
    union { float f; uint32_t u; } v; v.f = f;
    uint32_t u = v.u;
    uint32_t r = (u + 0x7fffu + ((u >> 16) & 1u)) >> 16;  // RNE
    return (ushort)r;
}
__device__ inline uint32_t pk2bf(uint32_t flo, uint32_t fhi) {  // two f32 bit-patterns -> packed bf16x2
    uint32_t lo = (flo + 0x7fffu + ((flo >> 16) & 1u)) >> 16;
    uint32_t hi = (fhi + 0x7fffu + ((fhi >> 16) & 1u)) >> 16;
    return lo | (hi << 16);
}

typedef __attribute__((ext_vector_type(8))) short bf16x8;
typedef __attribute__((ext_vector_type(4))) float f32x4;

// ---------- weight transpose+cast: W[1024,1024] f32 -> Wt[1024,1024] bf16 ----------
__global__ void transpose1024(const float* __restrict__ Wq, const float* __restrict__ Wk,
                              const float* __restrict__ Wv, const float* __restrict__ Wo,
                              ushort* __restrict__ WqT, ushort* __restrict__ WkT,
                              ushort* __restrict__ WvT, ushort* __restrict__ WoT) {
    const float* in; ushort* out;
    switch (blockIdx.z) {
        case 0: in = Wq; out = WqT; break;
        case 1: in = Wk; out = WkT; break;
        case 2: in = Wv; out = WvT; break;
        default: in = Wo; out = WoT; break;
    }
    __shared__ ushort tile[64][65];
    const int t = threadIdx.x;
    const int c = t & 63, rq = t >> 6;
    const int bx = blockIdx.x * 64, by = blockIdx.y * 64;
#pragma unroll
    for (int i = 0; i < 16; ++i) {
        int r = i * 4 + rq;
        tile[r][c] = f2bf(in[(size_t)(by + r) * 1024 + bx + c]);
    }
    __syncthreads();
#pragma unroll
    for (int i = 0; i < 16; ++i) {
        int r = i * 4 + rq;
        out[(size_t)(bx + r) * 1024 + by + c] = tile[c][r];
    }
}

// ---------- bf16-MFMA GEMM: C[M,N] = A[M,K] @ Bt[N,K]^T ----------
// A is f32 (converted on the fly) or bf16; C stored as f32 or bf16.
// 128x128 tile, BK=64, 4 waves 2x2, each wave 4x4 of 16x16x32 MFMA.
// Register-staged LDS; row stride 72 ushorts (144 B, 16B-aligned).
#define LDA 72
template <bool A_F32, bool C_F32>
__global__ __launch_bounds__(256)
void gemm_bt(const void* __restrict__ A_, const ushort* __restrict__ Bt,
             void* __restrict__ C_, int M, int N, int K) {
    const float*  Af = (const float*)A_;
    const ushort* Ab = (const ushort*)A_;
    __shared__ __attribute__((aligned(16))) ushort As[128 * LDA];
    __shared__ __attribute__((aligned(16))) ushort Bs[128 * LDA];
    const int t = threadIdx.x;
    const int lane = t & 63, wave = t >> 6;
    const int wm = wave >> 1, wn = wave & 1;
    const int quad = lane >> 4, l16 = lane & 15;
    const int m0 = blockIdx.y * 128, n0 = blockIdx.x * 128;

    const f32x4 zero = {0.f, 0.f, 0.f, 0.f};
    f32x4 acc[4][4];
#pragma unroll
    for (int i = 0; i < 4; ++i)
#pragma unroll
        for (int j = 0; j < 4; ++j) acc[i][j] = zero;

    for (int k0 = 0; k0 < K; k0 += 64) {
        uint4 aS[4], bS[4];
#pragma unroll
        for (int i = 0; i < 4; ++i) {
            const int s = t + i * 256;          // 1024 slots = 128 rows x 8 granules
            const int r = s >> 3, g = s & 7;
            if (A_F32) {
                // 8 f32 -> 8 bf16 (RNE), packed into uint4
                const uint4 lo = *(const uint4*)&Af[(size_t)(m0 + r) * K + (size_t)(k0 + g * 8)];
                const uint4 hi = *(const uint4*)&Af[(size_t)(m0 + r) * K + (size_t)(k0 + g * 8) + 4];
                aS[i].x = pk2bf(lo.x, lo.y);
                aS[i].y = pk2bf(lo.z, lo.w);
                aS[i].z = pk2bf(hi.x, hi.y);
                aS[i].w = pk2bf(hi.z, hi.w);
            } else {
                aS[i] = *(const uint4*)&Ab[(size_t)(m0 + r) * K + (size_t)(k0 + g * 8)];
            }
            bS[i] = *(const uint4*)&Bt[(size_t)(n0 + r) * K + (size_t)(k0 + g * 8)];
        }
        __syncthreads();                        // prev iter's LDS reads done
#pragma unroll
        for (int i = 0; i < 4; ++i) {
            const int s = t + i * 256;
            const int r = s >> 3, g = s & 7;
            *(uint4*)&As[r * LDA + g * 8] = aS[i];
            *(uint4*)&Bs[r * LDA + g * 8] = bS[i];
        }
        __syncthreads();
#pragma unroll
        for (int ks = 0; ks < 2; ++ks) {
            bf16x8 af[4], bfr[4];
            const int gk = ks * 4 + quad;       // A[m][k]: m=lane&15, k=quad*8+j
#pragma unroll
            for (int mt = 0; mt < 4; ++mt) {
                const int r = wm * 64 + mt * 16 + l16;
                af[mt] = *(const bf16x8*)&As[r * LDA + gk * 8];
            }
#pragma unroll
            for (int nt = 0; nt < 4; ++nt) {
                const int r = wn * 64 + nt * 16 + l16;
                bfr[nt] = *(const bf16x8*)&Bs[r * LDA + gk * 8];
            }
#pragma unroll
            for (int mt = 0; mt < 4; ++mt)
#pragma unroll
                for (int nt = 0; nt < 4; ++nt)
                    acc[mt][nt] = __builtin_amdgcn_mfma_f32_16x16x32_bf16(
                        af[mt], bfr[nt], acc[mt][nt], 0, 0, 0);
        }
    }
    // C/D layout: col = lane&15, row = quad*4 + reg  [m89/m91 verified]
#pragma unroll
    for (int mt = 0; mt < 4; ++mt)
#pragma unroll
        for (int nt = 0; nt < 4; ++nt)
#pragma unroll
            for (int r4 = 0; r4 < 4; ++r4) {
                const int row = m0 + wm * 64 + mt * 16 + quad * 4 + r4;
                const int col = n0 + wn * 64 + nt * 16 + l16;
                if (C_F32) ((float*)C_)[(size_t)row * N + col] = acc[mt][nt][r4];
                else       ((ushort*)C_)[(size_t)row * N + col] = f2bf(acc[mt][nt][r4]);
            }
}

// ---------- attention: per (b,h) 64x64 tile, VALU f32, bias f32 ----------
#define PADQ 72
__global__ __launch_bounds__(256)
void attn64(const ushort* __restrict__ Q, const ushort* __restrict__ K,
            const ushort* __restrict__ V, const float* __restrict__ bias,
            ushort* __restrict__ O) {
    __shared__ __attribute__((aligned(16))) ushort Qs[64 * PADQ];
    __shared__ __attribute__((aligned(16))) ushort Ks[64 * PADQ];
    __shared__ __attribute__((aligned(16))) ushort Vs[64 * PADQ];
    __shared__ float S[64 * 65];
    __shared__ float rmax_[64], rinv_[64];
    const int t = threadIdx.x;
    const int b = blockIdx.x >> 4, h = blockIdx.x & 15;
    const size_t base = (size_t)b * 64 * 1024 + (size_t)h * 64;

#pragma unroll
    for (int i = 0; i < 2; ++i) {
        int slot = t + i * 256;
        int r = slot >> 3, g = slot & 7;
        size_t go = base + (size_t)r * 1024 + (size_t)g * 8;
        *(uint4*)&Qs[r * PADQ + g * 8] = *(const uint4*)&Q[go];
        *(uint4*)&Ks[r * PADQ + g * 8] = *(const uint4*)&K[go];
        *(uint4*)&Vs[r * PADQ + g * 8] = *(const uint4*)&V[go];
    }
    __syncthreads();

    const int ti = t >> 4, tj = t & 15;
    const int i0 = ti * 4, j0 = tj * 4;
    // S = Q K^T / 8 + bias
    float acc[4][4] = {};
    for (int d = 0; d < 64; d += 2) {
        float q[4][2], k[4][2];
#pragma unroll
        for (int a = 0; a < 4; ++a) {
            q[a][0] = bf2f(Qs[(i0 + a) * PADQ + d]);
            q[a][1] = bf2f(Qs[(i0 + a) * PADQ + d + 1]);
            k[a][0] = bf2f(Ks[(j0 + a) * PADQ + d]);
            k[a][1] = bf2f(Ks[(j0 + a) * PADQ + d + 1]);
        }
#pragma unroll
        for (int a = 0; a < 4; ++a)
#pragma unroll
            for (int bb = 0; bb < 4; ++bb)
                acc[a][bb] += q[a][0] * k[bb][0] + q[a][1] * k[bb][1];
    }
#pragma unroll
    for (int a = 0; a < 4; ++a)
#pragma unroll
        for (int bb = 0; bb < 4; ++bb)
            S[(i0 + a) * 65 + j0 + bb] =
                acc[a][bb] * 0.125f + bias[(h * 64 + i0 + a) * 64 + j0 + bb];
    __syncthreads();

    if (t < 64) {
        float m = -1e30f;
        for (int j = 0; j < 64; ++j) m = fmaxf(m, S[t * 65 + j]);
        float s = 0.f;
        for (int j = 0; j < 64; ++j) s += __expf(S[t * 65 + j] - m);
        rmax_[t] = m; rinv_[t] = 1.f / s;
    }
    __syncthreads();
#pragma unroll
    for (int a = 0; a < 4; ++a)
#pragma unroll
        for (int bb = 0; bb < 4; ++bb) {
            int i = i0 + a, j = j0 + bb;
            S[i * 65 + j] = __expf(S[i * 65 + j] - rmax_[i]) * rinv_[i];
        }
    __syncthreads();

    // O = P V : thread owns rows i0..i0+3, out cols d0..d0+3
    const int d0 = tj * 4;
    float o[4][4] = {};
    for (int j = 0; j < 64; ++j) {
        ushort4 vr = *(const ushort4*)&Vs[j * PADQ + d0];
        float v0 = bf2f(vr.x), v1 = bf2f(vr.y), v2 = bf2f(vr.z), v3 = bf2f(vr.w);
#pragma unroll
        for (int a = 0; a < 4; ++a) {
            float p = S[(i0 + a) * 65 + j];
            o[a][0] += p * v0; o[a][1] += p * v1; o[a][2] += p * v2; o[a][3] += p * v3;
        }
    }
#pragma unroll
    for (int a = 0; a < 4; ++a) {
        ushort4 pk;
        pk.x = f2bf(o[a][0]); pk.y = f2bf(o[a][1]);
        pk.z = f2bf(o[a][2]); pk.w = f2bf(o[a][3]);
        *(ushort4*)&O[base + (size_t)(i0 + a) * 1024 + d0] = pk;  // in-place over Q region
    }
}

extern "C" void kernel_launch(void* const* d_in, const int* in_sizes, int n_in,
                              void* d_out, int out_size, void* d_ws, size_t ws_size,
                              hipStream_t stream) {
    const float* x    = (const float*)d_in[0];   // [512,64,1024] f32
    const float* bias = (const float*)d_in[1];   // [1,16,64,64]  f32
    const float* Wq   = (const float*)d_in[2];
    const float* Wk   = (const float*)d_in[3];
    const float* Wv   = (const float*)d_in[4];
    const float* Wo   = (const float*)d_in[5];
    float* out = (float*)d_out;                  // [512,64,1024] f32

    const size_t D = 1024;
    const int CHUNK_B = 128;               // batches per chunk
    const int NCHUNK  = 512 / CHUNK_B;     // 4
    const size_t CROWS = (size_t)CHUNK_B * 64;   // 8192 rows per chunk
    const size_t CELEM = CROWS * D;              // 8.39M elements

    // ws layout (58.7 MB): 4 transposed bf16 weights (8.4 MB) + bf16 Q/K/V chunk bufs.
    ushort* WqT = (ushort*)d_ws;
    ushort* WkT = WqT + D * D;
    ushort* WvT = WkT + D * D;
    ushort* WoT = WvT + D * D;
    ushort* Qc  = WoT + D * D;             // 16.8 MB
    ushort* Kc  = Qc + CELEM;              // 16.8 MB
    ushort* Vc  = Kc + CELEM;              // 16.8 MB

    transpose1024<<<dim3(16, 16, 4), 256, 0, stream>>>(Wq, Wk, Wv, Wo, WqT, WkT, WvT, WoT);

    for (int c = 0; c < NCHUNK; ++c) {
        const float* xc = x + (size_t)c * CELEM;
        gemm_bt<true, false><<<dim3(8, 64), 256, 0, stream>>>(xc, WqT, Qc, (int)CROWS, 1024, 1024);
        gemm_bt<true, false><<<dim3(8, 64), 256, 0, stream>>>(xc, WkT, Kc, (int)CROWS, 1024, 1024);
        gemm_bt<true, false><<<dim3(8, 64), 256, 0, stream>>>(xc, WvT, Vc, (int)CROWS, 1024, 1024);
        attn64<<<CHUNK_B * 16, 256, 0, stream>>>(Qc, Kc, Vc, bias, Qc);
        gemm_bt<false, true><<<dim3(8, 64), 256, 0, stream>>>(Qc, WoT, out + (size_t)c * CELEM,
                                                              (int)CROWS, 1024, 1024);
    }
}